// Round 13
// baseline (500.292 us; speedup 1.0000x reference)
//
#include <hip/hip_runtime.h>
#include <stdint.h>

// MoE top-1: router (fp32) + grouped bf16-MFMA GEMM over expert-sorted tokens.
// R13: fuse router + weight-transpose into one block-partitioned launch (k_prep)
//      so their independent memory streams co-schedule (serial ~85us -> ~60us).
//      GEMM = exact R10/R12 structure (2-phase 128^2, verified ceiling).
// ws layout (bytes):
//   0          : xb   bf16 [N][1024]  bf16(x), TOKEN order       (64 MB)
//   67108864   : h    bf16 [N][2048]  relu(x@W1+b1), SORTED      (128 MB)
//   201326592  : W1t  bf16 [8][2048][1024]                       (32 MB)
//   234881024  : W2t  bf16 [8][1024][2048]                       (32 MB)
//   268435456  : aux  int[4096]: cnt[0..7] cursor[8..15] ntiles[16]
//                tile_e[128..] tile_r0[512..] tile_r1[896..]     (16 KB, memset 0)
//   268451840  : routes     int[N]
//   268582912  : tok_of_pos int[N]   -> total 268,713,984 B

#define NTOK   32768
#define DIN    1024
#define DH     2048
#define DOUT   1024
#define NEXP   8

typedef unsigned short u16;
typedef __bf16 bf16x8 __attribute__((ext_vector_type(8)));
typedef float  f32x4  __attribute__((ext_vector_type(4)));
typedef unsigned short us8 __attribute__((ext_vector_type(8)));
typedef const __attribute__((address_space(1))) void gvoid_t;
typedef __attribute__((address_space(3))) void svoid_t;

__device__ __forceinline__ u16 f2bf(float f) {
  union { float f; uint32_t u; } v; v.f = f;
  return (u16)((v.u + 0x7FFFu + ((v.u >> 16) & 1u)) >> 16);  // RNE, no NaN in data
}

// ---------------- fused prep: blocks [0,512) = router (64 tokens each);
// blocks [512, 512+8192) = weight transpose tiles. Independent memory streams
// co-scheduled in one launch. Router per-token math identical to R12.
__global__ __launch_bounds__(256) void k_prep(
    const float* __restrict__ x, const float* __restrict__ Wr,
    const float* __restrict__ br, float* __restrict__ probs,
    int* __restrict__ routes, u16* __restrict__ xb, int* __restrict__ aux,
    const float* __restrict__ W1, u16* __restrict__ W1t,
    const float* __restrict__ W2, u16* __restrict__ W2t)
{
  __shared__ union {
    struct { float wr[NEXP * DIN]; int hist[NEXP]; } r;
    float tile[64][65];
  } sm;
  int tid = threadIdx.x;

  if (blockIdx.x < 512) {
    // ---------- router ----------
    if (tid < NEXP) sm.r.hist[tid] = 0;
    for (int idx = tid; idx < DIN * NEXP / 4; idx += 256) {
      float4 v = ((const float4*)Wr)[idx];
      int k = idx >> 1, r = (idx & 1) * 4;
      sm.r.wr[(r + 0) * DIN + k] = v.x;
      sm.r.wr[(r + 1) * DIN + k] = v.y;
      sm.r.wr[(r + 2) * DIN + k] = v.z;
      sm.r.wr[(r + 3) * DIN + k] = v.w;
    }
    __syncthreads();
    int lane = tid & 63, wv = tid >> 6;
    int base = (blockIdx.x * 4 + wv) * 16;
    for (int it = 0; it < 16; ++it) {
      int t = base + it;
      const float* xr = x + (size_t)t * DIN;
      u16* xbrow = xb + (size_t)t * DIN;
      float acc[NEXP];
      #pragma unroll
      for (int e = 0; e < NEXP; ++e) acc[e] = 0.f;
      #pragma unroll
      for (int i = 0; i < 4; ++i) {
        int k = i * 256 + lane * 4;
        float4 xv = *(const float4*)(xr + k);
        ushort4 o;
        o.x = f2bf(xv.x); o.y = f2bf(xv.y); o.z = f2bf(xv.z); o.w = f2bf(xv.w);
        *(ushort4*)(xbrow + k) = o;          // bf16 copy, token order
        #pragma unroll
        for (int e = 0; e < NEXP; ++e) {
          float4 w4 = *(const float4*)(sm.r.wr + e * DIN + k);
          acc[e] += xv.x * w4.x + xv.y * w4.y + xv.z * w4.z + xv.w * w4.w;
        }
      }
      #pragma unroll
      for (int off = 32; off >= 1; off >>= 1) {
        #pragma unroll
        for (int e = 0; e < NEXP; ++e) acc[e] += __shfl_xor(acc[e], off, 64);
      }
      if (lane == 0) {
        float l[NEXP], m = -1e30f;
        #pragma unroll
        for (int e = 0; e < NEXP; ++e) { l[e] = acc[e] + br[e]; m = fmaxf(m, l[e]); }
        float p[NEXP], s = 0.f;
        #pragma unroll
        for (int e = 0; e < NEXP; ++e) { p[e] = expf(l[e] - m); s += p[e]; }
        float inv = 1.f / s;
        int am = 0; float best = l[0];
        #pragma unroll
        for (int e = 1; e < NEXP; ++e) if (l[e] > best) { best = l[e]; am = e; }
        float4 pa = {p[0] * inv, p[1] * inv, p[2] * inv, p[3] * inv};
        float4 pb = {p[4] * inv, p[5] * inv, p[6] * inv, p[7] * inv};
        float4* pd = (float4*)(probs + (size_t)t * NEXP);
        pd[0] = pa; pd[1] = pb;
        routes[t] = am;
        atomicAdd(&sm.r.hist[am], 1);
      }
    }
    __syncthreads();
    if (tid < NEXP && sm.r.hist[tid]) atomicAdd(&aux[tid], sm.r.hist[tid]);
  } else {
    // ---------- weight transpose+convert: [E][K][Nn] f32 -> [E][Nn][K] bf16 ----------
    int t2 = blockIdx.x - 512;
    const float* src; u16* dst; int K, Nn, e, k0, n0;
    if (t2 < 4096) {                         // W1: 16 k-tiles x 32 n-tiles per e
      src = W1; dst = W1t; K = DIN; Nn = DH;
      e = t2 >> 9; int r = t2 & 511; k0 = (r & 15) * 64; n0 = (r >> 4) * 64;
    } else {                                 // W2: 32 k-tiles x 16 n-tiles per e
      t2 -= 4096;
      src = W2; dst = W2t; K = DH; Nn = DOUT;
      e = t2 >> 9; int r = t2 & 511; k0 = (r & 31) * 64; n0 = (r >> 5) * 64;
    }
    const float* s = src + ((size_t)e * K + k0) * Nn + n0;
    int r = tid >> 6, c = tid & 63;
    #pragma unroll
    for (int i = 0; i < 16; ++i)
      sm.tile[r + i * 4][c] = s[(size_t)(r + i * 4) * Nn + c];
    __syncthreads();
    u16* d = dst + ((size_t)e * Nn + n0) * K + k0;
    int kg = (tid & 7) * 8, nr0 = tid >> 3;
    #pragma unroll
    for (int p = 0; p < 2; ++p) {
      int nr = nr0 + p * 32;
      us8 o;
      #pragma unroll
      for (int j = 0; j < 8; ++j) o[j] = f2bf(sm.tile[kg + j][nr]);
      *(us8*)(d + (size_t)nr * K + kg) = o;
    }
  }
}

// ---------------- slot assignment + fused prefix/tile-map ----------------
__global__ __launch_bounds__(256) void k_assign(
    const int* __restrict__ routes, int* __restrict__ aux,
    int* __restrict__ tok_of_pos, float* __restrict__ counts_out)
{
  __shared__ int s_off[NEXP];
  int tid = threadIdx.x;
  if (tid < NEXP) {
    int off = 0;
    for (int k = 0; k < tid; ++k) off += aux[k];
    s_off[tid] = off;
  }
  __syncthreads();
  if (blockIdx.x == 0 && tid == 0) {
    int off = 0, tb = 0;
    for (int e = 0; e < NEXP; ++e) {
      int c = aux[e];
      counts_out[e] = (float)c;
      int tiles = (c + 127) >> 7;
      for (int tt = 0; tt < tiles; ++tt) {
        aux[128 + tb] = e;
        aux[512 + tb] = off + tt * 128;
        aux[896 + tb] = off + c;
        ++tb;
      }
      off += c;
    }
    aux[16] = tb;
  }
  int t = blockIdx.x * 256 + tid;
  int e = routes[t];
  int lane = tid & 63;
  int p = 0;
  #pragma unroll
  for (int ee = 0; ee < NEXP; ++ee) {
    unsigned long long m = __ballot(e == ee);
    int base = 0;
    if (lane == 0 && m) base = atomicAdd(&aux[8 + ee], (int)__popcll(m));
    base = __shfl(base, 0, 64);
    if (e == ee)
      p = s_off[ee] + base + (int)__popcll(m & ((1ull << lane) - 1ull));
  }
  tok_of_pos[p] = t;
}

// ---------------- grouped GEMM (EXACT R10/R12): m97 geometry, 128x128 tile,
// BK=64, 4 waves (2x2), per-wave 64x64 out. Single-buffered 2-barrier loop.
// XCD-chunked 1D grid, N-fastest within chunk (T1). GATHER=1: A rows via
// tok_of_pos (per-lane global_load_lds sources). 4 blocks/CU.
// MODE 0: H = relu(A@B^T + bias) -> bf16   MODE 1: out[tok] = A@B^T + bias -> f32 scatter
template<int MODE, int GATHER>
__global__ __launch_bounds__(256, 4) void k_gemm(
    const u16* __restrict__ A, const u16* __restrict__ Bt,
    const float* __restrict__ bias, u16* __restrict__ Hout,
    float* __restrict__ Yout, const int* __restrict__ tok_of_pos,
    const int* __restrict__ aux, int K, int Nn, int nbyl)
{
  int nwg = gridDim.x;                 // divisible by 8
  int bid = blockIdx.x;
  int wg  = (bid & 7) * (nwg >> 3) + (bid >> 3);
  int by  = wg & ((1 << nbyl) - 1);    // N-fastest within the XCD chunk
  int bx  = wg >> nbyl;
  if (bx >= aux[16]) return;
  int e  = aux[128 + bx];
  int r0 = aux[512 + bx];
  int r1 = aux[896 + bx];
  int bn0 = by << 7;

  __shared__ __align__(16) u16 As[128 * 64];   // [row][k], 128B rows, slot-swizzled
  __shared__ __align__(16) u16 Bs[128 * 64];

  int tid = threadIdx.x;
  int lane = tid & 63, wv = tid >> 6;
  int wr = wv >> 1, wc = wv & 1;
  const u16* Be = Bt + (size_t)e * Nn * K;

  // A-row ids this thread stages (row = r*32 + tid/8), gathered if needed
  int tk[4];
  #pragma unroll
  for (int r = 0; r < 4; ++r) {
    int gr = r0 + r * 32 + (tid >> 3);
    gr = gr < NTOK ? gr : NTOK - 1;
    tk[r] = GATHER ? tok_of_pos[gr] : gr;
  }

  auto stage = [&](int kt) {
    int k0 = kt * 64;
    #pragma unroll
    for (int r = 0; r < 4; ++r) {              // A: 16 KB
      int L = (r * 256 + tid) * 16;
      int sl = ((L >> 4) & 7) ^ ((L >> 7) & 7);   // pre-swizzle global source (G21)
      __builtin_amdgcn_global_load_lds(
          (gvoid_t*)((const char*)(A + (size_t)tk[r] * K + k0) + sl * 16),
          (svoid_t*)((char*)As + L), 16, 0, 0);
    }
    #pragma unroll
    for (int r = 0; r < 4; ++r) {              // B: 16 KB
      int L = (r * 256 + tid) * 16;
      int row = L >> 7;
      int sl = ((L >> 4) & 7) ^ (row & 7);
      __builtin_amdgcn_global_load_lds(
          (gvoid_t*)((const char*)(Be + (size_t)(bn0 + row) * K + k0) + sl * 16),
          (svoid_t*)((char*)Bs + L), 16, 0, 0);
    }
  };

  f32x4 acc[4][4];
  #pragma unroll
  for (int i = 0; i < 4; ++i)
    #pragma unroll
    for (int j = 0; j < 4; ++j)
      acc[i][j] = (f32x4){0.f, 0.f, 0.f, 0.f};

  int KT = K >> 6;
  stage(0);
  for (int kt = 0; kt < KT; ++kt) {
    __syncthreads();
    const char* As_c = (const char*)As;
    const char* Bs_c = (const char*)Bs;
    #pragma unroll
    for (int kk = 0; kk < 2; ++kk) {
      int sw = ((kk * 4 + (lane >> 4)) ^ (lane & 7)) << 4;   // swizzled 16B slot
      bf16x8 a[4], b[4];
      #pragma unroll
      for (int f = 0; f < 4; ++f)
        a[f] = *(const bf16x8*)(As_c + (wr * 64 + f * 16 + (lane & 15)) * 128 + sw);
      #pragma unroll
      for (int f = 0; f < 4; ++f)
        b[f] = *(const bf16x8*)(Bs_c + (wc * 64 + f * 16 + (lane & 15)) * 128 + sw);
      #pragma unroll
      for (int i = 0; i < 4; ++i)
        #pragma unroll
        for (int j = 0; j < 4; ++j)
          acc[i][j] = __builtin_amdgcn_mfma_f32_16x16x32_bf16(a[i], b[j], acc[i][j], 0, 0, 0);
    }
    __syncthreads();
    if (kt + 1 < KT) stage(kt + 1);
  }

  const float* be = bias + (size_t)e * Nn;
  float bv[4];
  #pragma unroll
  for (int j = 0; j < 4; ++j) bv[j] = be[bn0 + wc * 64 + j * 16 + (lane & 15)];
  #pragma unroll
  for (int i = 0; i < 4; ++i) {
    #pragma unroll
    for (int q = 0; q < 4; ++q) {
      int r = r0 + wr * 64 + i * 16 + (lane >> 4) * 4 + q;  // C/D: col=lane&15, row=(lane>>4)*4+q [m89]
      if (r < r1) {
        if (MODE == 0) {
          u16* dst = Hout + (size_t)r * Nn + bn0 + wc * 64 + (lane & 15);
          #pragma unroll
          for (int j = 0; j < 4; ++j)
            dst[j * 16] = f2bf(fmaxf(acc[i][j][q] + bv[j], 0.f));
        } else {
          int tok = tok_of_pos[r];
          float* dst = Yout + (size_t)tok * Nn + bn0 + wc * 64 + (lane & 15);
          #pragma unroll
          for (int j = 0; j < 4; ++j)
            dst[j * 16] = acc[i][j][q] + bv[j];
        }
      }
    }
  }
}

extern "C" void kernel_launch(void* const* d_in, const int* in_sizes, int n_in,
                              void* d_out, int out_size, void* d_ws, size_t ws_size,
                              hipStream_t stream)
{
  const float* x  = (const float*)d_in[0];
  const float* Wr = (const float*)d_in[1];
  const float* br = (const float*)d_in[2];
  const float* W1 = (const float*)d_in[3];
  const float* b1 = (const float*)d_in[4];
  const float* W2 = (const float*)d_in[5];
  const float* b2 = (const float*)d_in[6];

  float* out    = (float*)d_out;                       // [N][1024]
  float* probs  = out + (size_t)NTOK * DOUT;           // [N][8]
  float* counts = probs + (size_t)NTOK * NEXP;         // [8]

  char* ws = (char*)d_ws;
  u16* xb          = (u16*)(ws);
  u16* h           = (u16*)(ws + 67108864);
  u16* W1t         = (u16*)(ws + 201326592);
  u16* W2t         = (u16*)(ws + 234881024);
  int* aux         = (int*)(ws + 268435456);
  int* routes      = (int*)(ws + 268451840);
  int* tok_of_pos  = (int*)(ws + 268582912);

  (void)hipMemsetAsync(aux, 0, 16384, stream);
  k_prep<<<512 + 8192, 256, 0, stream>>>(x, Wr, br, probs, routes, xb, aux, W1, W1t, W2, W2t);
  k_assign<<<NTOK / 256, 256, 0, stream>>>(routes, aux, tok_of_pos, counts);
  k_gemm<0, 1><<<264 * 16, 256, 0, stream>>>(xb, W1t, b1, h, nullptr, tok_of_pos, aux, DIN, DH, 4);
  k_gemm<1, 0><<<264 * 8, 256, 0, stream>>>(h, W2t, b2, nullptr, out, tok_of_pos, aux, DH, DOUT, 3);
}

// Round 14
// 450.742 us; speedup vs baseline: 1.1099x; 1.1099x over previous
//
#include <hip/hip_runtime.h>
#include <stdint.h>

// MoE top-1: router (fp32) + grouped bf16-MFMA GEMM over expert-sorted tokens.
// R14: revert R13 fusion (union-LDS halved transpose occupancy). R12 structure +
//      (a) router 1024 blocks / 8 tok-wave (more TLP, identical math),
//      (b) assign fused into the transpose launch at its own 32B LDS footprint.
//      GEMM = exact R10/R12 (2-phase 128^2, verified ceiling ~800 TF/GEMM).
// ws layout (bytes):
//   0          : xb   bf16 [N][1024]  bf16(x), TOKEN order       (64 MB)
//   67108864   : h    bf16 [N][2048]  relu(x@W1+b1), SORTED      (128 MB)
//   201326592  : W1t  bf16 [8][2048][1024]                       (32 MB)
//   234881024  : W2t  bf16 [8][1024][2048]                       (32 MB)
//   268435456  : aux  int[4096]: cnt[0..7] cursor[8..15] ntiles[16]
//                tile_e[128..] tile_r0[512..] tile_r1[896..]     (16 KB, memset 0)
//   268451840  : routes     int[N]
//   268582912  : tok_of_pos int[N]   -> total 268,713,984 B

#define NTOK   32768
#define DIN    1024
#define DH     2048
#define DOUT   1024
#define NEXP   8

typedef unsigned short u16;
typedef __bf16 bf16x8 __attribute__((ext_vector_type(8)));
typedef float  f32x4  __attribute__((ext_vector_type(4)));
typedef unsigned short us8 __attribute__((ext_vector_type(8)));
typedef const __attribute__((address_space(1))) void gvoid_t;
typedef __attribute__((address_space(3))) void svoid_t;

__device__ __forceinline__ u16 f2bf(float f) {
  union { float f; uint32_t u; } v; v.f = f;
  return (u16)((v.u + 0x7FFFu + ((v.u >> 16) & 1u)) >> 16);  // RNE, no NaN in data
}

// ---------------- router: 8 tokens/wave (1024 blocks, 4 blk/CU TLP);
// logits, softmax, argmax, bf16(x), fused per-block count.
// Per-token math bit-identical to R12.
__global__ __launch_bounds__(256) void k_router(
    const float* __restrict__ x, const float* __restrict__ Wr,
    const float* __restrict__ br, float* __restrict__ probs,
    int* __restrict__ routes, u16* __restrict__ xb, int* __restrict__ aux)
{
  __shared__ float wr_s[NEXP * DIN];  // transposed Wr: [e][k]
  __shared__ int hist[NEXP];
  int tid = threadIdx.x;
  if (tid < NEXP) hist[tid] = 0;
  for (int idx = tid; idx < DIN * NEXP / 4; idx += 256) {
    float4 v = ((const float4*)Wr)[idx];
    int k = idx >> 1, r = (idx & 1) * 4;
    wr_s[(r + 0) * DIN + k] = v.x;
    wr_s[(r + 1) * DIN + k] = v.y;
    wr_s[(r + 2) * DIN + k] = v.z;
    wr_s[(r + 3) * DIN + k] = v.w;
  }
  __syncthreads();
  int lane = tid & 63, wv = tid >> 6;
  int base = (blockIdx.x * 4 + wv) * 8;
  for (int it = 0; it < 8; ++it) {
    int t = base + it;
    const float* xr = x + (size_t)t * DIN;
    u16* xbrow = xb + (size_t)t * DIN;
    float acc[NEXP];
    #pragma unroll
    for (int e = 0; e < NEXP; ++e) acc[e] = 0.f;
    #pragma unroll
    for (int i = 0; i < 4; ++i) {
      int k = i * 256 + lane * 4;
      float4 xv = *(const float4*)(xr + k);
      ushort4 o;
      o.x = f2bf(xv.x); o.y = f2bf(xv.y); o.z = f2bf(xv.z); o.w = f2bf(xv.w);
      *(ushort4*)(xbrow + k) = o;            // bf16 copy, token order
      #pragma unroll
      for (int e = 0; e < NEXP; ++e) {
        float4 w4 = *(const float4*)(wr_s + e * DIN + k);
        acc[e] += xv.x * w4.x + xv.y * w4.y + xv.z * w4.z + xv.w * w4.w;
      }
    }
    #pragma unroll
    for (int off = 32; off >= 1; off >>= 1) {
      #pragma unroll
      for (int e = 0; e < NEXP; ++e) acc[e] += __shfl_xor(acc[e], off, 64);
    }
    if (lane == 0) {
      float l[NEXP], m = -1e30f;
      #pragma unroll
      for (int e = 0; e < NEXP; ++e) { l[e] = acc[e] + br[e]; m = fmaxf(m, l[e]); }
      float p[NEXP], s = 0.f;
      #pragma unroll
      for (int e = 0; e < NEXP; ++e) { p[e] = expf(l[e] - m); s += p[e]; }
      float inv = 1.f / s;
      int am = 0; float best = l[0];
      #pragma unroll
      for (int e = 1; e < NEXP; ++e) if (l[e] > best) { best = l[e]; am = e; }
      float4 pa = {p[0] * inv, p[1] * inv, p[2] * inv, p[3] * inv};
      float4 pb = {p[4] * inv, p[5] * inv, p[6] * inv, p[7] * inv};
      float4* pd = (float4*)(probs + (size_t)t * NEXP);
      pd[0] = pa; pd[1] = pb;
      routes[t] = am;
      atomicAdd(&hist[am], 1);
    }
  }
  __syncthreads();
  if (tid < NEXP && hist[tid]) atomicAdd(&aux[tid], hist[tid]);
}

// ---------------- fused transpose + assign (both depend only on router).
// Blocks [0,128): slot assignment (+ block 0: prefix/tile-map + counts out).
// Blocks [128, 128+8192): weight transpose tiles. LDS footprint = transpose's
// 16.6KB (assign uses 32B) — no union inflation (R13 lesson).
__global__ __launch_bounds__(256) void k_trasgn(
    const float* __restrict__ W1, u16* __restrict__ W1t,
    const float* __restrict__ W2, u16* __restrict__ W2t,
    const int* __restrict__ routes, int* __restrict__ aux,
    int* __restrict__ tok_of_pos, float* __restrict__ counts_out)
{
  int tid = threadIdx.x;
  if (blockIdx.x < 128) {
    // ---------- assign ----------
    __shared__ int s_off[NEXP];
    if (tid < NEXP) {
      int off = 0;
      for (int k = 0; k < tid; ++k) off += aux[k];
      s_off[tid] = off;
    }
    __syncthreads();
    if (blockIdx.x == 0 && tid == 0) {
      int off = 0, tb = 0;
      for (int e = 0; e < NEXP; ++e) {
        int c = aux[e];
        counts_out[e] = (float)c;
        int tiles = (c + 127) >> 7;
        for (int tt = 0; tt < tiles; ++tt) {
          aux[128 + tb] = e;
          aux[512 + tb] = off + tt * 128;
          aux[896 + tb] = off + c;
          ++tb;
        }
        off += c;
      }
      aux[16] = tb;
    }
    int t = blockIdx.x * 256 + tid;
    int e = routes[t];
    int lane = tid & 63;
    int p = 0;
    #pragma unroll
    for (int ee = 0; ee < NEXP; ++ee) {
      unsigned long long m = __ballot(e == ee);
      int base = 0;
      if (lane == 0 && m) base = atomicAdd(&aux[8 + ee], (int)__popcll(m));
      base = __shfl(base, 0, 64);
      if (e == ee)
        p = s_off[ee] + base + (int)__popcll(m & ((1ull << lane) - 1ull));
    }
    tok_of_pos[p] = t;
  } else {
    // ---------- weight transpose+convert: [E][K][Nn] f32 -> [E][Nn][K] bf16 ----------
    __shared__ float tile[64][65];
    int t2 = blockIdx.x - 128;
    const float* src; u16* dst; int K, Nn, e, k0, n0;
    if (t2 < 4096) {                         // W1: 16 k-tiles x 32 n-tiles per e
      src = W1; dst = W1t; K = DIN; Nn = DH;
      e = t2 >> 9; int r = t2 & 511; k0 = (r & 15) * 64; n0 = (r >> 4) * 64;
    } else {                                 // W2: 32 k-tiles x 16 n-tiles per e
      t2 -= 4096;
      src = W2; dst = W2t; K = DH; Nn = DOUT;
      e = t2 >> 9; int r = t2 & 511; k0 = (r & 31) * 64; n0 = (r >> 5) * 64;
    }
    const float* s = src + ((size_t)e * K + k0) * Nn + n0;
    int r = tid >> 6, c = tid & 63;
    #pragma unroll
    for (int i = 0; i < 16; ++i)
      tile[r + i * 4][c] = s[(size_t)(r + i * 4) * Nn + c];
    __syncthreads();
    u16* d = dst + ((size_t)e * Nn + n0) * K + k0;
    int kg = (tid & 7) * 8, nr0 = tid >> 3;
    #pragma unroll
    for (int p = 0; p < 2; ++p) {
      int nr = nr0 + p * 32;
      us8 o;
      #pragma unroll
      for (int j = 0; j < 8; ++j) o[j] = f2bf(tile[kg + j][nr]);
      *(us8*)(d + (size_t)nr * K + kg) = o;
    }
  }
}

// ---------------- grouped GEMM (EXACT R10/R12): m97 geometry, 128x128 tile,
// BK=64, 4 waves (2x2), per-wave 64x64 out. Single-buffered 2-barrier loop.
// XCD-chunked 1D grid, N-fastest within chunk (T1). GATHER=1: A rows via
// tok_of_pos (per-lane global_load_lds sources). 4 blocks/CU.
// MODE 0: H = relu(A@B^T + bias) -> bf16   MODE 1: out[tok] = A@B^T + bias -> f32 scatter
template<int MODE, int GATHER>
__global__ __launch_bounds__(256, 4) void k_gemm(
    const u16* __restrict__ A, const u16* __restrict__ Bt,
    const float* __restrict__ bias, u16* __restrict__ Hout,
    float* __restrict__ Yout, const int* __restrict__ tok_of_pos,
    const int* __restrict__ aux, int K, int Nn, int nbyl)
{
  int nwg = gridDim.x;                 // divisible by 8
  int bid = blockIdx.x;
  int wg  = (bid & 7) * (nwg >> 3) + (bid >> 3);
  int by  = wg & ((1 << nbyl) - 1);    // N-fastest within the XCD chunk
  int bx  = wg >> nbyl;
  if (bx >= aux[16]) return;
  int e  = aux[128 + bx];
  int r0 = aux[512 + bx];
  int r1 = aux[896 + bx];
  int bn0 = by << 7;

  __shared__ __align__(16) u16 As[128 * 64];   // [row][k], 128B rows, slot-swizzled
  __shared__ __align__(16) u16 Bs[128 * 64];

  int tid = threadIdx.x;
  int lane = tid & 63, wv = tid >> 6;
  int wr = wv >> 1, wc = wv & 1;
  const u16* Be = Bt + (size_t)e * Nn * K;

  // A-row ids this thread stages (row = r*32 + tid/8), gathered if needed
  int tk[4];
  #pragma unroll
  for (int r = 0; r < 4; ++r) {
    int gr = r0 + r * 32 + (tid >> 3);
    gr = gr < NTOK ? gr : NTOK - 1;
    tk[r] = GATHER ? tok_of_pos[gr] : gr;
  }

  auto stage = [&](int kt) {
    int k0 = kt * 64;
    #pragma unroll
    for (int r = 0; r < 4; ++r) {              // A: 16 KB
      int L = (r * 256 + tid) * 16;
      int sl = ((L >> 4) & 7) ^ ((L >> 7) & 7);   // pre-swizzle global source (G21)
      __builtin_amdgcn_global_load_lds(
          (gvoid_t*)((const char*)(A + (size_t)tk[r] * K + k0) + sl * 16),
          (svoid_t*)((char*)As + L), 16, 0, 0);
    }
    #pragma unroll
    for (int r = 0; r < 4; ++r) {              // B: 16 KB
      int L = (r * 256 + tid) * 16;
      int row = L >> 7;
      int sl = ((L >> 4) & 7) ^ (row & 7);
      __builtin_amdgcn_global_load_lds(
          (gvoid_t*)((const char*)(Be + (size_t)(bn0 + row) * K + k0) + sl * 16),
          (svoid_t*)((char*)Bs + L), 16, 0, 0);
    }
  };

  f32x4 acc[4][4];
  #pragma unroll
  for (int i = 0; i < 4; ++i)
    #pragma unroll
    for (int j = 0; j < 4; ++j)
      acc[i][j] = (f32x4){0.f, 0.f, 0.f, 0.f};

  int KT = K >> 6;
  stage(0);
  for (int kt = 0; kt < KT; ++kt) {
    __syncthreads();
    const char* As_c = (const char*)As;
    const char* Bs_c = (const char*)Bs;
    #pragma unroll
    for (int kk = 0; kk < 2; ++kk) {
      int sw = ((kk * 4 + (lane >> 4)) ^ (lane & 7)) << 4;   // swizzled 16B slot
      bf16x8 a[4], b[4];
      #pragma unroll
      for (int f = 0; f < 4; ++f)
        a[f] = *(const bf16x8*)(As_c + (wr * 64 + f * 16 + (lane & 15)) * 128 + sw);
      #pragma unroll
      for (int f = 0; f < 4; ++f)
        b[f] = *(const bf16x8*)(Bs_c + (wc * 64 + f * 16 + (lane & 15)) * 128 + sw);
      #pragma unroll
      for (int i = 0; i < 4; ++i)
        #pragma unroll
        for (int j = 0; j < 4; ++j)
          acc[i][j] = __builtin_amdgcn_mfma_f32_16x16x32_bf16(a[i], b[j], acc[i][j], 0, 0, 0);
    }
    __syncthreads();
    if (kt + 1 < KT) stage(kt + 1);
  }

  const float* be = bias + (size_t)e * Nn;
  float bv[4];
  #pragma unroll
  for (int j = 0; j < 4; ++j) bv[j] = be[bn0 + wc * 64 + j * 16 + (lane & 15)];
  #pragma unroll
  for (int i = 0; i < 4; ++i) {
    #pragma unroll
    for (int q = 0; q < 4; ++q) {
      int r = r0 + wr * 64 + i * 16 + (lane >> 4) * 4 + q;  // C/D: col=lane&15, row=(lane>>4)*4+q [m89]
      if (r < r1) {
        if (MODE == 0) {
          u16* dst = Hout + (size_t)r * Nn + bn0 + wc * 64 + (lane & 15);
          #pragma unroll
          for (int j = 0; j < 4; ++j)
            dst[j * 16] = f2bf(fmaxf(acc[i][j][q] + bv[j], 0.f));
        } else {
          int tok = tok_of_pos[r];
          float* dst = Yout + (size_t)tok * Nn + bn0 + wc * 64 + (lane & 15);
          #pragma unroll
          for (int j = 0; j < 4; ++j)
            dst[j * 16] = acc[i][j][q] + bv[j];
        }
      }
    }
  }
}

extern "C" void kernel_launch(void* const* d_in, const int* in_sizes, int n_in,
                              void* d_out, int out_size, void* d_ws, size_t ws_size,
                              hipStream_t stream)
{
  const float* x  = (const float*)d_in[0];
  const float* Wr = (const float*)d_in[1];
  const float* br = (const float*)d_in[2];
  const float* W1 = (const float*)d_in[3];
  const float* b1 = (const float*)d_in[4];
  const float* W2 = (const float*)d_in[5];
  const float* b2 = (const float*)d_in[6];

  float* out    = (float*)d_out;                       // [N][1024]
  float* probs  = out + (size_t)NTOK * DOUT;           // [N][8]
  float* counts = probs + (size_t)NTOK * NEXP;         // [8]

  char* ws = (char*)d_ws;
  u16* xb          = (u16*)(ws);
  u16* h           = (u16*)(ws + 67108864);
  u16* W1t         = (u16*)(ws + 201326592);
  u16* W2t         = (u16*)(ws + 234881024);
  int* aux         = (int*)(ws + 268435456);
  int* routes      = (int*)(ws + 268451840);
  int* tok_of_pos  = (int*)(ws + 268582912);

  (void)hipMemsetAsync(aux, 0, 16384, stream);
  k_router<<<NTOK / 32, 256, 0, stream>>>(x, Wr, br, probs, routes, xb, aux);
  k_trasgn<<<128 + 8192, 256, 0, stream>>>(W1, W1t, W2, W2t, routes, aux, tok_of_pos, counts);
  k_gemm<0, 1><<<264 * 16, 256, 0, stream>>>(xb, W1t, b1, h, nullptr, tok_of_pos, aux, DIN, DH, 4);
  k_gemm<1, 0><<<264 * 8, 256, 0, stream>>>(h, W2t, b2, nullptr, out, tok_of_pos, aux, DH, DOUT, 3);
}